// Round 6
// baseline (62.452 us; speedup 1.0000x reference)
//
#include <hip/hip_runtime.h>

typedef __bf16 bf16x8 __attribute__((ext_vector_type(8)));
typedef float f32x4 __attribute__((ext_vector_type(4)));

// Problem constants: B=4, Cin=64, Cout=64, H=W=128, K=3, PAD=1, KK=9

// ---------------- Kernel 1: x (NCHW f32) -> x_t (NHWC bf16) ----------------
__global__ __launch_bounds__(256) void k_xt(const float* __restrict__ x,
                                            __bf16* __restrict__ xt) {
  __shared__ float tile[64 * 129];
  int b = blockIdx.x >> 7;
  int y = blockIdx.x & 127;
  int t = threadIdx.x;
#pragma unroll
  for (int it = 0; it < 32; ++it) {
    int r = it * 256 + t;           // 8192 elems: 64c x 128w
    int c = r >> 7, xw = r & 127;
    tile[c * 129 + xw] = x[((b * 64 + c) * 128 + y) * 128 + xw];
  }
  __syncthreads();
#pragma unroll
  for (int it = 0; it < 32; ++it) {
    int r = it * 256 + t;
    int xw = r >> 6, c = r & 63;
    xt[((b * 128 + y) * 128 + xw) * 64 + c] = (__bf16)tile[c * 129 + xw];
  }
}

// ------- Kernel 2: weight preps (merged) -------
__global__ __launch_bounds__(256) void k_prep(const float* __restrict__ wt,
                                              const float* __restrict__ ow,
                                              __bf16* __restrict__ wb,
                                              __bf16* __restrict__ owb) {
  int i = blockIdx.x * 256 + threadIdx.x;
  if (i < 36864) {
    int k = i >> 12, rem = i & 4095, o = rem >> 6, c = rem & 63;
    wb[i] = (__bf16)wt[(o * 64 + c) * 9 + k];
  } else if (i < 36864 + 18432) {
    int j = i - 36864;
    int k = j >> 11, rem = j & 2047, o = rem >> 6, c = rem & 63;
    float v = (o < 18) ? ow[(o * 64 + c) * 9 + k] : 0.0f;
    owb[j] = (__bf16)v;
  }
}

// ---------------- Kernel 3: offset conv -> offs (global f32) ----------------
// grid 1024 = (2 wtiles) x (128 h) x (4 b); 256 threads (4 waves)
// Stage0: raw 3x66x64c tile -> LDS (zero-padded, branch-free); then MFMA.
__global__ __launch_bounds__(256) void k_off(
    const __bf16* __restrict__ xt, const __bf16* __restrict__ owb,
    const float* __restrict__ ob, float* __restrict__ offs) {
  __shared__ __bf16 Xs[3 * 66 * 72];  // 28512 B

  int t = threadIdx.x;
  int wtile = blockIdx.x & 1;
  int h = (blockIdx.x >> 1) & 127;
  int b = blockIdx.x >> 8;
  int w0 = wtile * 64;

  int lane = t & 63, wid = t >> 6;
  int row = lane & 15, quad = lane >> 4;
  const __bf16* xb = xt + (size_t)b * 128 * 128 * 64;

  // Stage0: rows h-1..h+1, pixels w0-1..w0+64, all 64c
#pragma unroll
  for (int it = 0; it < 7; ++it) {
    int idx8 = it * 256 + t;  // 1584 chunks of 8 elems
    if (idx8 < 1584) {
      int c8 = idx8 & 7;
      int jr = idx8 >> 3;  // 0..197
      int jj = jr % 66;
      int ki = jr / 66;
      int gy = h - 1 + ki;
      int gx = w0 - 1 + jj;
      bf16x8 v = {};
      if (((unsigned)gy < 128u) & ((unsigned)gx < 128u))
        v = *(const bf16x8*)(xb + (gy * 128 + gx) * 64 + c8 * 8);
      *(bf16x8*)&Xs[(ki * 66 + jj) * 72 + c8 * 8] = v;
    }
  }
  __syncthreads();

  // offset conv MFMA: M=18pad32, N=64 pix, K=576; B-frags from LDS
  int woA = (wid >> 1) * 16;
  int wpA = (wid & 1) * 32;
  f32x4 accA[2];
  accA[0] = f32x4{0.f, 0.f, 0.f, 0.f};
  accA[1] = f32x4{0.f, 0.f, 0.f, 0.f};
#pragma unroll
  for (int k = 0; k < 9; ++k) {
    int ki = k / 3, kj = k % 3;
    const __bf16* ap = owb + k * 2048 + (woA + row) * 64 + quad * 8;
    bf16x8 afr0 = *(const bf16x8*)(ap);
    bf16x8 afr1 = *(const bf16x8*)(ap + 32);
#pragma unroll
    for (int n = 0; n < 2; ++n) {
      int j = wpA + n * 16 + row + kj;  // 0..65
      const __bf16* lp = &Xs[(ki * 66 + j) * 72 + quad * 8];
      bf16x8 b0 = *(const bf16x8*)(lp);
      bf16x8 b1 = *(const bf16x8*)(lp + 32);
      accA[n] = __builtin_amdgcn_mfma_f32_16x16x32_bf16(afr0, b0, accA[n], 0, 0, 0);
      accA[n] = __builtin_amdgcn_mfma_f32_16x16x32_bf16(afr1, b1, accA[n], 0, 0, 0);
    }
  }
  // epilogue to global offs[b][co][h][w]; col=lane&15 (pix), row=quad*4+r (co)
  int qr = quad * 4;
#pragma unroll
  for (int n = 0; n < 2; ++n) {
#pragma unroll
    for (int r = 0; r < 4; ++r) {
      int co = woA + qr + r;
      if (co < 18)
        offs[((b * 18 + co) * 128 + h) * 128 + w0 + wpA + n * 16 + row] =
            accA[n][r] + ob[co];
    }
  }
}

// ---- sampling helpers (shared by prologue and steady-state) ----
__device__ __forceinline__ void sample_issue(const __bf16* __restrict__ xb,
                                             int cg, float dy, float dx,
                                             float base_y, float base_x,
                                             bf16x8 g[8], float wts[4]) {
  float py = dy + base_y, px = dx + base_x;
  float fy = floorf(py), fx = floorf(px);
  float ly = py - fy, lx = px - fx;
  int y0 = (int)fy, x0 = (int)fx;
  int y1 = y0 + 1, x1 = x0 + 1;
  bool vy0 = (unsigned)y0 < 128u, vy1 = (unsigned)y1 < 128u;
  bool vx0 = (unsigned)x0 < 128u, vx1 = (unsigned)x1 < 128u;
  wts[0] = (vy0 && vx0) ? (1.f - ly) * (1.f - lx) : 0.f;
  wts[1] = (vy0 && vx1) ? (1.f - ly) * lx : 0.f;
  wts[2] = (vy1 && vx0) ? ly * (1.f - lx) : 0.f;
  wts[3] = (vy1 && vx1) ? ly * lx : 0.f;
  int yc0 = min(max(y0, 0), 127), yc1 = min(max(y1, 0), 127);
  int xc0 = min(max(x0, 0), 127), xc1 = min(max(x1, 0), 127);
  const __bf16* xc = xb + cg * 16;
  const bf16x8* p00 = (const bf16x8*)(xc + (yc0 * 128 + xc0) * 64);
  const bf16x8* p01 = (const bf16x8*)(xc + (yc0 * 128 + xc1) * 64);
  const bf16x8* p10 = (const bf16x8*)(xc + (yc1 * 128 + xc0) * 64);
  const bf16x8* p11 = (const bf16x8*)(xc + (yc1 * 128 + xc1) * 64);
  g[0] = p00[0]; g[1] = p00[1];
  g[2] = p01[0]; g[3] = p01[1];
  g[4] = p10[0]; g[5] = p10[1];
  g[6] = p11[0]; g[7] = p11[1];
}

__device__ __forceinline__ void interp_store(__bf16* __restrict__ Sp,
                                             const bf16x8 g[8],
                                             const float wts[4]) {
  bf16x8 o0, o1;
#pragma unroll
  for (int j = 0; j < 8; ++j) {
    float s0 = wts[0] * (float)g[0][j] + wts[1] * (float)g[2][j] +
               wts[2] * (float)g[4][j] + wts[3] * (float)g[6][j];
    float s1 = wts[0] * (float)g[1][j] + wts[1] * (float)g[3][j] +
               wts[2] * (float)g[5][j] + wts[3] * (float)g[7][j];
    o0[j] = (__bf16)s0;
    o1[j] = (__bf16)s1;
  }
  *(bf16x8*)(Sp) = o0;
  *(bf16x8*)(Sp + 8) = o1;
}

// ---------------- Kernel 4: main GEMM with pipelined sampling ----------------
// grid 1024 = (2 wtiles) x (128 h) x (4 b); 256 threads (4 waves)
// Double-buffered S; tap k+1's gathers issued BEFORE tap k's MFMA (T14);
// one barrier per tap.
__global__ __launch_bounds__(256, 4) void k_main(
    const __bf16* __restrict__ xt, const __bf16* __restrict__ wb,
    const float* __restrict__ offs, const float* __restrict__ bias,
    float* __restrict__ out) {
  __shared__ __bf16 S[2][64 * 72];  // 2 x 9216 B

  int t = threadIdx.x;
  int wtile = blockIdx.x & 1;
  int h = (blockIdx.x >> 1) & 127;
  int b = blockIdx.x >> 8;
  int w0 = wtile * 64;

  int pix = t >> 2, cg = t & 3;
  int w = w0 + pix;
  int lane = t & 63, wid = t >> 6;
  int row = lane & 15, quad = lane >> 4;
  int woB = (wid >> 1) * 32, wpB = (wid & 1) * 32;
  const __bf16* xb = xt + (size_t)b * 128 * 128 * 64;

  // preload this pixel's 18 offsets into registers
  float ody[9], odx[9];
  const float* offp = offs + ((size_t)(b * 18) * 128 + h) * 128 + w;
#pragma unroll
  for (int k = 0; k < 9; ++k) {
    ody[k] = offp[(2 * k) * 16384];
    odx[k] = offp[(2 * k + 1) * 16384];
  }

  f32x4 acc[2][2];
#pragma unroll
  for (int i = 0; i < 2; ++i)
#pragma unroll
    for (int j = 0; j < 2; ++j) acc[i][j] = f32x4{0.f, 0.f, 0.f, 0.f};

  // prologue: tap 0 -> S[0]
  {
    bf16x8 g[8];
    float wts[4];
    sample_issue(xb, cg, ody[0], odx[0], (float)(h - 1), (float)(w - 1), g, wts);
    interp_store(&S[0][pix * 72 + cg * 16], g, wts);
  }
  __syncthreads();

#pragma unroll
  for (int k = 0; k < 9; ++k) {
    // issue tap k+1's gathers before consuming tap k
    bf16x8 gn[8];
    float wn[4];
    if (k < 8) {
      int kn = k + 1;
      sample_issue(xb, cg, ody[kn], odx[kn], (float)(h + kn / 3 - 1),
                   (float)(w + kn % 3 - 1), gn, wn);
    }
    // MFMA tap k from S[k&1]; A-frags direct from L2-hot wb
    {
      const __bf16* wk = wb + k * 4096;
      const __bf16* Sb = S[k & 1];
#pragma unroll
      for (int ks = 0; ks < 2; ++ks) {
        int c0 = ks * 32 + quad * 8;
        bf16x8 afr[2], bfr[2];
#pragma unroll
        for (int mi = 0; mi < 2; ++mi)
          afr[mi] = *(const bf16x8*)(wk + (woB + mi * 16 + row) * 64 + c0);
#pragma unroll
        for (int ni = 0; ni < 2; ++ni)
          bfr[ni] = *(const bf16x8*)&Sb[(wpB + ni * 16 + row) * 72 + c0];
#pragma unroll
        for (int mi = 0; mi < 2; ++mi)
#pragma unroll
          for (int ni = 0; ni < 2; ++ni)
            acc[mi][ni] = __builtin_amdgcn_mfma_f32_16x16x32_bf16(
                afr[mi], bfr[ni], acc[mi][ni], 0, 0, 0);
      }
    }
    if (k < 8) {
      interp_store(&S[(k + 1) & 1][pix * 72 + cg * 16], gn, wn);
      __syncthreads();
    }
  }
  // epilogue: col=lane&15 (pix), row=quad*4+r (o)
  {
    int col = lane & 15;
    int qr = quad * 4;
#pragma unroll
    for (int mi = 0; mi < 2; ++mi) {
#pragma unroll
      for (int ni = 0; ni < 2; ++ni) {
#pragma unroll
        for (int r = 0; r < 4; ++r) {
          int o = woB + mi * 16 + qr + r;
          int pw = w0 + wpB + ni * 16 + col;
          out[((b * 64 + o) * 128 + h) * 128 + pw] = acc[mi][ni][r] + bias[o];
        }
      }
    }
  }
}

extern "C" void kernel_launch(void* const* d_in, const int* in_sizes, int n_in,
                              void* d_out, int out_size, void* d_ws,
                              size_t ws_size, hipStream_t stream) {
  const float* x = (const float*)d_in[0];       // (4,64,128,128)
  const float* ow = (const float*)d_in[1];      // (18,64,3,3)
  const float* ob = (const float*)d_in[2];      // (18,)
  const float* wt = (const float*)d_in[3];      // (64,64,3,3)
  const float* bias = (const float*)d_in[4];    // (64,)
  float* out = (float*)d_out;                   // (4,64,128,128)

  char* ws = (char*)d_ws;
  __bf16* xt = (__bf16*)ws;                      // 8,388,608 B
  __bf16* wb = (__bf16*)(ws + 8388608);          // 73,728 B
  __bf16* owb = (__bf16*)(ws + 8388608 + 73728); // 36,864 B
  float* offs = (float*)(ws + 8388608 + 73728 + 36864);  // 4,718,592 B

  k_xt<<<512, 256, 0, stream>>>(x, xt);
  k_prep<<<216, 256, 0, stream>>>(wt, ow, wb, owb);
  k_off<<<1024, 256, 0, stream>>>(xt, owb, ob, offs);
  k_main<<<1024, 256, 0, stream>>>(xt, wb, offs, bias, out);
}